// Round 11
// baseline (679.710 us; speedup 1.0000x reference)
//
#include <hip/hip_runtime.h>

namespace {

constexpr int SEQ = 2048, BATCH = 1024, IN = 10, H = 20;
constexpr int XS  = 32;                  // x steps per LDS chunk
constexpr int XRW = 16;                  // ints per step-row: A pairs @0..4, B pairs @8..12
constexpr float L2E = 1.4426950408889634f;
constexpr float K2  = -2.0f * L2E;       // carried scale on c:  c' = K2 * c

typedef _Float16 h2t __attribute__((ext_vector_type(2)));

__device__ __forceinline__ float rcpf(float x) { return __builtin_amdgcn_rcpf(x); }
__device__ __forceinline__ float xp2(float x)  { return __builtin_amdgcn_exp2f(x); }

__device__ __forceinline__ int pk(float a, float b) {
    auto v = __builtin_amdgcn_cvt_pkrtz(a, b);
    int i; __builtin_memcpy(&i, &v, 4); return i;
}
__device__ __forceinline__ float dot2(int a, int b, float c) {
    h2t ha, hb; __builtin_memcpy(&ha, &a, 4); __builtin_memcpy(&hb, &b, 4);
    return __builtin_amdgcn_fdot2(ha, hb, c, false);
}
// lane^1 (quad_perm [1,0,3,2] = 0xB1)
__device__ __forceinline__ float dpp_x1(float v) {
    int i; __builtin_memcpy(&i, &v, 4);
    int r = __builtin_amdgcn_update_dpp(0, i, 0xB1, 0xF, 0xF, true);
    float f; __builtin_memcpy(&f, &r, 4); return f;
}
// lane^2 (quad_perm [2,3,0,1] = 0x4E)
__device__ __forceinline__ float dpp_x2(float v) {
    int i; __builtin_memcpy(&i, &v, 4);
    int r = __builtin_amdgcn_update_dpp(0, i, 0x4E, 0xF, 0xF, true);
    float f; __builtin_memcpy(&f, &r, 4); return f;
}

__launch_bounds__(64)
__global__ void lstm_bidir(const float* __restrict__ x,
                           const float* __restrict__ h0,
                           const float* __restrict__ c0,
                           const float* __restrict__ w_ih_f, const float* __restrict__ w_hh_f,
                           const float* __restrict__ b_ih_f, const float* __restrict__ b_hh_f,
                           const float* __restrict__ w_ih_b, const float* __restrict__ w_hh_b,
                           const float* __restrict__ b_ih_b, const float* __restrict__ b_hh_b,
                           float* __restrict__ out, float* __restrict__ h_n, float* __restrict__ c_n)
{
    const int dir  = blockIdx.y;
    const int bA   = blockIdx.x * 2;      // two same-direction chains per one-wave block
    const int bB   = bA + 1;
    const int lane = threadIdx.x;
    const int u    = lane >> 1;           // unit 0..31 (20..31 junk, clamped)
    const int gp   = lane & 1;            // 0: gates {i,f}, 1: gates {g~,o}
    const int ur   = (u < H) ? u : (H - 1);
    const bool red = (gp == 0) && (u < H);

    // pair-publish: lanes 4k,4k+1 hold the CORRECT (h2k,h2k+1) pair after dpp_x2;
    // lanes 4k+2,4k+3 hold the swapped pair -> route them to dump slots.
    // Stores are UNCONDITIONAL (every lane, every step): a may-alias store in each
    // thread's loop body is what stops LLVM from CSE-hoisting the hl loads
    // (the R9/R10 correctness bug: guarded stores -> 54 lanes read stale h forever).
    const bool okp  = ((lane & 2) == 0) && (u < H);
    const int  offA = okp ? (lane >> 2) : (32 + lane);        // real A: 0..9,  dump 32..95
    const int  offB = okp ? (16 + (lane >> 2)) : (96 + lane); // real B: 16..25, dump 96..159

    const float* w_ih = dir ? w_ih_b : w_ih_f;
    const float* w_hh = dir ? w_hh_b : w_hh_f;
    const float* bi   = dir ? b_ih_b : b_ih_f;
    const float* bh   = dir ? b_hh_b : b_hh_f;

    __shared__ __align__(16) int xlds[2][XS * XRW];   // x chunks, fp16-pair packed (4 KiB)
    __shared__ __align__(16) int hl[160];             // A pairs[0..9], B pairs[16..25], dumps

    // ---- gate rows in registers (SHARED by both chains), pre-scaled by -log2e ----
    const int g0 = gp * 2 * H + ur, g1 = g0 + H;      // gp0: {i,f}, gp1: {g~,o}
    const float sc0 = gp ? K2 : (-L2E);
    const float sc1 = -L2E;
    const float na0 = gp ? (2.0f * K2) : 1.0f;        // gp1 n0 = K2*tanh(g~)
    const float nd0 = gp ? (-K2) : 0.0f;

    int wh[2][10], wi[2][5]; float bias[2];
    #pragma unroll
    for (int k = 0; k < 10; ++k) {
        wh[0][k] = pk(w_hh[g0 * H + 2 * k] * sc0, w_hh[g0 * H + 2 * k + 1] * sc0);
        wh[1][k] = pk(w_hh[g1 * H + 2 * k] * sc1, w_hh[g1 * H + 2 * k + 1] * sc1);
    }
    #pragma unroll
    for (int k = 0; k < 5; ++k) {
        wi[0][k] = pk(w_ih[g0 * IN + 2 * k] * sc0, w_ih[g0 * IN + 2 * k + 1] * sc0);
        wi[1][k] = pk(w_ih[g1 * IN + 2 * k] * sc1, w_ih[g1 * IN + 2 * k + 1] * sc1);
    }
    bias[0] = (bi[g0] + bh[g0]) * sc0;
    bias[1] = (bi[g1] + bh[g1]) * sc1;

    float cA = c0[(dir * BATCH + bA) * H + ur] * K2;  // carried pre-scaled
    float hA = h0[(dir * BATCH + bA) * H + ur];
    float cB = c0[(dir * BATCH + bB) * H + ur] * K2;
    float hB = h0[(dir * BATCH + bB) * H + ur];

    // initial publish (full exec for DPP, unconditional stores)
    hl[offA] = pk(hA, dpp_x2(hA));
    hl[offB] = pk(hB, dpp_x2(hB));

    // ---- x staging: both chains' columns are adjacent (20 floats = 10 float2 per row) ----
    const float*    xbase = x + bA * IN;
    const ptrdiff_t xstep = dir ? -(ptrdiff_t)(BATCH * IN) : (ptrdiff_t)(BATCH * IN);
    const size_t    xoff0 = (size_t)(dir ? SEQ - 1 : 0) * (BATCH * IN);

    float2 pend[5];
    auto issue_chunk = [&](int s0) {
        #pragma unroll
        for (int i = 0; i < 5; ++i) {
            const int e  = lane + 64 * i;             // 0..319
            const int ss = e / 10, j = e % 10;
            pend[i] = *(const float2*)(xbase + xoff0 + (ptrdiff_t)(s0 + ss) * xstep + 2 * j);
        }
    };
    auto write_chunk = [&](int buf) {
        #pragma unroll
        for (int i = 0; i < 5; ++i) {
            const int e  = lane + 64 * i;
            const int ss = e / 10, j = e % 10;
            xlds[buf][ss * XRW + j + (j >= 5 ? 3 : 0)] = pk(pend[i].x, pend[i].y);
        }
    };

    issue_chunk(0);  write_chunk(0);
    issue_chunk(XS);                                  // next chunk pending in regs

    const ptrdiff_t ostep = dir ? -(ptrdiff_t)(BATCH * 2 * H) : (ptrdiff_t)(BATCH * 2 * H);
    float* optrA = out + (size_t)(dir ? SEQ - 1 : 0) * (BATCH * 2 * H) + bA * (2 * H) + dir * H + ur;
    float* optrB = optrA + 2 * H;

    // one chain's step: reads its x slice + h pairs, returns new h-pair (int) to publish
    auto chain_step = [&](const int* xr, int hb, float& c, float& hv) -> int {
        const int4 xA4 = *(const int4*)xr;
        const int  x4  = xr[4];
        const int  xq[5] = { xA4.x, xA4.y, xA4.z, xA4.w, x4 };

        const int4 h04 = *(const int4*)&hl[hb];
        const int4 h48 = *(const int4*)&hl[hb + 4];
        const int2 h89 = *(const int2*)&hl[hb + 8];
        const int  hp[10] = { h04.x, h04.y, h04.z, h04.w, h48.x, h48.y, h48.z, h48.w, h89.x, h89.y };

        float a0 = bias[0], a1 = bias[1], p0 = 0.0f, p1 = 0.0f;
        #pragma unroll
        for (int k = 0; k < 3; ++k) {
            a0 = dot2(xq[k], wi[0][k], a0);
            a1 = dot2(xq[k], wi[1][k], a1);
        }
        #pragma unroll
        for (int k = 3; k < 5; ++k) {
            p0 = dot2(xq[k], wi[0][k], p0);
            p1 = dot2(xq[k], wi[1][k], p1);
        }
        #pragma unroll
        for (int k = 0; k < 5; ++k) {
            a0 = dot2(hp[k],     wh[0][k],     a0);
            a1 = dot2(hp[k],     wh[1][k],     a1);
            p0 = dot2(hp[k + 5], wh[0][k + 5], p0);
            p1 = dot2(hp[k + 5], wh[1][k + 5], p1);
        }
        a0 += p0;  a1 += p1;

        const float n0 = fmaf(na0, rcpf(1.0f + xp2(a0)), nd0);  // gp0: sig(i)  gp1: K2*tanh(g~)
        const float n1 = rcpf(1.0f + xp2(a1));                  // gp0: sig(f)  gp1: sig(o)
        const float m0 = dpp_x1(n0);
        const float m1 = dpp_x1(n1);
        const float F  = gp ? m1 : n1;                          // sig(f)
        c = fmaf(F, c, n0 * m0);                                // c' = F*c' + K2*sig(i)*tanh(g~)
        const float th = fmaf(2.0f, rcpf(1.0f + xp2(c)), -1.0f);
        const float o  = gp ? n1 : m1;                          // sig(o)
        hv = o * th;
        return pk(hv, dpp_x2(hv));
    };

    for (int s0 = 0; s0 < SEQ; s0 += XS) {
        const int buf = (s0 >> 5) & 1;
        #pragma unroll 2
        for (int ss = 0; ss < XS; ++ss) {
            const int* xr = &xlds[buf][ss * XRW];
            const int pairA = chain_step(xr,     0,  cA, hA);
            const int pairB = chain_step(xr + 8, 16, cB, hB);

            // unconditional publishes (every lane stores -> no load-CSE across steps;
            // in-order same-wave DS makes them visible to next step's reads)
            hl[offA] = pairA;
            hl[offB] = pairB;

            if (red) {
                __builtin_nontemporal_store(hA, optrA);
                __builtin_nontemporal_store(hB, optrB);
            }
            optrA += ostep;  optrB += ostep;
        }
        // ---- chunk boundary: publish pending chunk, prefetch next-next ----
        if (s0 + XS < SEQ) {
            write_chunk(buf ^ 1);                    // counted-vmcnt wait on old loads only
            if (s0 + 2 * XS < SEQ) issue_chunk(s0 + 2 * XS);
        }
    }

    if (red) {
        h_n[(dir * BATCH + bA) * H + ur] = hA;
        c_n[(dir * BATCH + bA) * H + ur] = cA * (1.0f / K2);
        h_n[(dir * BATCH + bB) * H + ur] = hB;
        c_n[(dir * BATCH + bB) * H + ur] = cB * (1.0f / K2);
    }
}

} // namespace

extern "C" void kernel_launch(void* const* d_in, const int* in_sizes, int n_in,
                              void* d_out, int out_size, void* d_ws, size_t ws_size,
                              hipStream_t stream)
{
    const float* x      = (const float*)d_in[0];
    const float* h0     = (const float*)d_in[1];
    const float* c0     = (const float*)d_in[2];
    const float* w_ih_f = (const float*)d_in[3];
    const float* w_hh_f = (const float*)d_in[4];
    const float* b_ih_f = (const float*)d_in[5];
    const float* b_hh_f = (const float*)d_in[6];
    const float* w_ih_b = (const float*)d_in[7];
    const float* w_hh_b = (const float*)d_in[8];
    const float* b_ih_b = (const float*)d_in[9];
    const float* b_hh_b = (const float*)d_in[10];

    float* out = (float*)d_out;
    float* h_n = out + (size_t)SEQ * BATCH * 2 * H;
    float* c_n = h_n + (size_t)2 * BATCH * H;

    dim3 grid(BATCH / 2, 2), block(64);
    hipLaunchKernelGGL(lstm_bidir, grid, block, 0, stream,
                       x, h0, c0, w_ih_f, w_hh_f, b_ih_f, b_hh_f,
                       w_ih_b, w_hh_b, b_ih_b, b_hh_b, out, h_n, c_n);
}

// Round 12
// 585.839 us; speedup vs baseline: 1.1602x; 1.1602x over previous
//
#include <hip/hip_runtime.h>

namespace {

constexpr int SEQ = 2048, BATCH = 1024, IN = 10, H = 20;
constexpr int XS  = 32;                  // x steps per LDS chunk
constexpr int XRW = 8;                   // ints per step-row in LDS (5 used)
constexpr float L2E = 1.4426950408889634f;
constexpr float K2  = -2.0f * L2E;       // carried scale on c:  c' = K2 * c

typedef _Float16 h2t __attribute__((ext_vector_type(2)));

__device__ __forceinline__ float rcpf(float x) { return __builtin_amdgcn_rcpf(x); }
__device__ __forceinline__ float xp2(float x)  { return __builtin_amdgcn_exp2f(x); }

__device__ __forceinline__ int pk(float a, float b) {
    auto v = __builtin_amdgcn_cvt_pkrtz(a, b);
    int i; __builtin_memcpy(&i, &v, 4); return i;
}
__device__ __forceinline__ float dot2(int a, int b, float c) {
    h2t ha, hb; __builtin_memcpy(&ha, &a, 4); __builtin_memcpy(&hb, &b, 4);
    return __builtin_amdgcn_fdot2(ha, hb, c, false);
}
// lane^1 (quad_perm [1,0,3,2] = 0xB1)
__device__ __forceinline__ float dpp_x1(float v) {
    int i; __builtin_memcpy(&i, &v, 4);
    int r = __builtin_amdgcn_update_dpp(0, i, 0xB1, 0xF, 0xF, true);
    float f; __builtin_memcpy(&f, &r, 4); return f;
}
// lane^2 (quad_perm [2,3,0,1] = 0x4E)
__device__ __forceinline__ float dpp_x2(float v) {
    int i; __builtin_memcpy(&i, &v, 4);
    int r = __builtin_amdgcn_update_dpp(0, i, 0x4E, 0xF, 0xF, true);
    float f; __builtin_memcpy(&f, &r, 4); return f;
}

template<int DIR>
__device__ __forceinline__ void run_dir(const float* __restrict__ x,
                                        const float* __restrict__ h0,
                                        const float* __restrict__ c0,
                                        const float* __restrict__ w_ih,
                                        const float* __restrict__ w_hh,
                                        const float* __restrict__ bi,
                                        const float* __restrict__ bh,
                                        float* __restrict__ out,
                                        float* __restrict__ h_n,
                                        float* __restrict__ c_n,
                                        int b, int lane,
                                        int* xlds, int* hl)
{
    const int u    = lane >> 1;           // unit 0..31 (20..31 junk, clamped)
    const int gp   = lane & 1;            // 0: gates {i,f}, 1: gates {g~,o}
    const int ur   = (u < H) ? u : (H - 1);
    const bool red = (gp == 0) && (u < H);

    // single-writer publish: lane 4k holds the correct (h2k,h2k+1) pair after dpp_x2.
    // ALL lanes store every step (dump slots for non-publishers) -> prevents LLVM
    // from CSE-hoisting the hl loads (R9/R10 lesson).
    const bool okp  = ((lane & 3) == 0) && (u < H);
    const int  hoff = okp ? (lane >> 2) : (16 + lane);    // real: 0..9, dump: 17..79

    // ---- gate rows in registers, fp16-packed, pre-scaled by -log2e (tanh row: K2) ----
    const int g0 = gp * 2 * H + ur, g1 = g0 + H;          // gp0: {i,f}, gp1: {g~,o}
    const float sc0 = gp ? K2 : (-L2E);
    const float sc1 = -L2E;
    const float na0 = gp ? (2.0f * K2) : 1.0f;            // gp1 n0 = K2*tanh(g~)
    const float nd0 = gp ? (-K2) : 0.0f;

    int wh[2][10], wi[2][5]; float bias[2];
    #pragma unroll
    for (int k = 0; k < 10; ++k) {
        wh[0][k] = pk(w_hh[g0 * H + 2 * k] * sc0, w_hh[g0 * H + 2 * k + 1] * sc0);
        wh[1][k] = pk(w_hh[g1 * H + 2 * k] * sc1, w_hh[g1 * H + 2 * k + 1] * sc1);
    }
    #pragma unroll
    for (int k = 0; k < 5; ++k) {
        wi[0][k] = pk(w_ih[g0 * IN + 2 * k] * sc0, w_ih[g0 * IN + 2 * k + 1] * sc0);
        wi[1][k] = pk(w_ih[g1 * IN + 2 * k] * sc1, w_ih[g1 * IN + 2 * k + 1] * sc1);
    }
    bias[0] = (bi[g0] + bh[g0]) * sc0;
    bias[1] = (bi[g1] + bh[g1]) * sc1;

    float c  = c0[(DIR * BATCH + b) * H + ur] * K2;       // carried pre-scaled
    float hv = h0[(DIR * BATCH + b) * H + ur];

    hl[hoff] = pk(hv, dpp_x2(hv));                        // initial publish (full exec)

    // ---- x chunk staging: 160 fp16-pairs/chunk, packed at stage time ----
    constexpr ptrdiff_t XSTEP = DIR ? -(ptrdiff_t)(BATCH * IN) : (ptrdiff_t)(BATCH * IN);
    constexpr ptrdiff_t XOFF0 = DIR ? (ptrdiff_t)(SEQ - 1) * (BATCH * IN) : 0;
    const float* xbase = x + b * IN + XOFF0;

    float2 pend[3];
    auto issue_chunk = [&](int s0) {
        #pragma unroll
        for (int i = 0; i < 3; ++i) {
            const int e = lane + 64 * i;
            if (i < 2 || lane < 32) {                     // e < 160
                const int ss = e / 5, j = e % 5;
                pend[i] = *(const float2*)(xbase + (ptrdiff_t)(s0 + ss) * XSTEP + 2 * j);
            }
        }
    };
    auto write_chunk = [&](int buf) {
        #pragma unroll
        for (int i = 0; i < 3; ++i) {
            const int e = lane + 64 * i;
            if (i < 2 || lane < 32)
                xlds[buf * (XS * XRW) + (e / 5) * XRW + (e % 5)] = pk(pend[i].x, pend[i].y);
        }
    };

    issue_chunk(0);  write_chunk(0);
    issue_chunk(XS);                                      // next chunk pending in regs

    // ---- out addressing: uniform 64-bit row index (SALU) + constant lane offset ----
    constexpr ptrdiff_t OSTEP  = DIR ? -(ptrdiff_t)(BATCH * 2 * H) : (ptrdiff_t)(BATCH * 2 * H);
    ptrdiff_t           orow   = DIR ? (ptrdiff_t)(SEQ - 1) * (BATCH * 2 * H) : 0;
    const int           oconst = b * (2 * H) + DIR * H + ur;

    for (int s0 = 0; s0 < SEQ; s0 += XS) {
        const int buf = (s0 >> 5) & 1;
        #pragma unroll 4
        for (int ss = 0; ss < XS; ++ss) {
            // ---- x row (wave-uniform broadcast, pre-packed fp16 pairs) ----
            const int* xr = &xlds[buf * (XS * XRW) + ss * XRW];
            const int4 xA4 = *(const int4*)xr;
            const int  x4  = xr[4];
            const int  xq[5] = { xA4.x, xA4.y, xA4.z, xA4.w, x4 };

            // ---- h pairs (published by previous step; same-wave DS is in-order) ----
            const int4 h04 = *(const int4*)&hl[0];
            const int4 h48 = *(const int4*)&hl[4];
            const int2 h89 = *(const int2*)&hl[8];
            const int  hp[10] = { h04.x, h04.y, h04.z, h04.w,
                                  h48.x, h48.y, h48.z, h48.w, h89.x, h89.y };

            // ---- 2 gates per lane, split accumulators (4 independent dot2 chains) ----
            float a0 = bias[0], a1 = bias[1], p0 = 0.0f, p1 = 0.0f;
            #pragma unroll
            for (int k = 0; k < 3; ++k) {
                a0 = dot2(xq[k], wi[0][k], a0);
                a1 = dot2(xq[k], wi[1][k], a1);
            }
            #pragma unroll
            for (int k = 3; k < 5; ++k) {
                p0 = dot2(xq[k], wi[0][k], p0);
                p1 = dot2(xq[k], wi[1][k], p1);
            }
            #pragma unroll
            for (int k = 0; k < 5; ++k) {
                a0 = dot2(hp[k],     wh[0][k],     a0);
                a1 = dot2(hp[k],     wh[1][k],     a1);
                p0 = dot2(hp[k + 5], wh[0][k + 5], p0);
                p1 = dot2(hp[k + 5], wh[1][k + 5], p1);
            }
            a0 += p0;  a1 += p1;

            // ---- nonlinearities (per-lane consts make i/f/g~/o uniform) ----
            const float n0 = fmaf(na0, rcpf(1.0f + xp2(a0)), nd0);  // gp0: sig(i)  gp1: K2*tanh(g~)
            const float n1 = rcpf(1.0f + xp2(a1));                  // gp0: sig(f)  gp1: sig(o)

            // ---- gate-pair exchange: 2 DPP + 2 selects ----
            const float m0 = dpp_x1(n0);
            const float m1 = dpp_x1(n1);
            const float F  = gp ? m1 : n1;                          // sig(f)
            c = fmaf(F, c, n0 * m0);                                // c' = F*c' + K2*sig(i)*tanh(g~)
            const float th = fmaf(2.0f, rcpf(1.0f + xp2(c)), -1.0f);
            const float o  = gp ? n1 : m1;                          // sig(o)
            hv = o * th;

            const int pair = pk(hv, dpp_x2(hv));                    // full exec DPP
            hl[hoff] = pair;                                        // unconditional publish
            if (red) __builtin_nontemporal_store(hv, out + orow + oconst);
            orow += OSTEP;                                          // uniform -> SALU
        }
        // ---- chunk boundary: publish pending chunk, prefetch next-next ----
        if (s0 + XS < SEQ) {
            write_chunk(buf ^ 1);                                   // counted-vmcnt wait
            if (s0 + 2 * XS < SEQ) issue_chunk(s0 + 2 * XS);
        }
    }

    if (red) {
        h_n[(DIR * BATCH + b) * H + ur] = hv;
        c_n[(DIR * BATCH + b) * H + ur] = c * (1.0f / K2);
    }
}

__launch_bounds__(64)
__global__ void lstm_bidir(const float* __restrict__ x,
                           const float* __restrict__ h0,
                           const float* __restrict__ c0,
                           const float* __restrict__ w_ih_f, const float* __restrict__ w_hh_f,
                           const float* __restrict__ b_ih_f, const float* __restrict__ b_hh_f,
                           const float* __restrict__ w_ih_b, const float* __restrict__ w_hh_b,
                           const float* __restrict__ b_ih_b, const float* __restrict__ b_hh_b,
                           float* __restrict__ out, float* __restrict__ h_n, float* __restrict__ c_n)
{
    __shared__ __align__(16) int xlds[2 * XS * XRW];   // x chunks, fp16-pair packed (2 KiB)
    __shared__ __align__(16) int hl[80];               // h pairs [0..9] + dump slots

    const int b    = blockIdx.x;
    const int lane = threadIdx.x;

    if (blockIdx.y == 0)
        run_dir<0>(x, h0, c0, w_ih_f, w_hh_f, b_ih_f, b_hh_f, out, h_n, c_n, b, lane, xlds, hl);
    else
        run_dir<1>(x, h0, c0, w_ih_b, w_hh_b, b_ih_b, b_hh_b, out, h_n, c_n, b, lane, xlds, hl);
}

} // namespace

extern "C" void kernel_launch(void* const* d_in, const int* in_sizes, int n_in,
                              void* d_out, int out_size, void* d_ws, size_t ws_size,
                              hipStream_t stream)
{
    const float* x      = (const float*)d_in[0];
    const float* h0     = (const float*)d_in[1];
    const float* c0     = (const float*)d_in[2];
    const float* w_ih_f = (const float*)d_in[3];
    const float* w_hh_f = (const float*)d_in[4];
    const float* b_ih_f = (const float*)d_in[5];
    const float* b_hh_f = (const float*)d_in[6];
    const float* w_ih_b = (const float*)d_in[7];
    const float* w_hh_b = (const float*)d_in[8];
    const float* b_ih_b = (const float*)d_in[9];
    const float* b_hh_b = (const float*)d_in[10];

    float* out = (float*)d_out;
    float* h_n = out + (size_t)SEQ * BATCH * 2 * H;
    float* c_n = h_n + (size_t)2 * BATCH * H;

    dim3 grid(BATCH, 2), block(64);
    hipLaunchKernelGGL(lstm_bidir, grid, block, 0, stream,
                       x, h0, c0, w_ih_f, w_hh_f, b_ih_f, b_hh_f,
                       w_ih_b, w_hh_b, b_ih_b, b_hh_b, out, h_n, c_n);
}

// Round 13
// 497.129 us; speedup vs baseline: 1.3673x; 1.1784x over previous
//
#include <hip/hip_runtime.h>

namespace {

constexpr int SEQ = 2048, BATCH = 1024, IN = 10, H = 20;
constexpr int XS  = 32;                  // x steps per LDS chunk
constexpr int XRW = 16;                  // ints per step-row: chain0 pairs @0..4, chain1 @8..12
constexpr float L2E = 1.4426950408889634f;
constexpr float K2  = -2.0f * L2E;       // carried scale on c:  c' = K2 * c

typedef _Float16 h2t __attribute__((ext_vector_type(2)));

__device__ __forceinline__ float rcpf(float x) { return __builtin_amdgcn_rcpf(x); }
__device__ __forceinline__ float xp2(float x)  { return __builtin_amdgcn_exp2f(x); }
__device__ __forceinline__ float sig2(float a) { return rcpf(1.0f + xp2(a)); } // sigmoid(-a/log2e)

__device__ __forceinline__ int pk(float a, float b) {
    auto v = __builtin_amdgcn_cvt_pkrtz(a, b);
    int i; __builtin_memcpy(&i, &v, 4); return i;
}
__device__ __forceinline__ float dot2(int a, int b, float c) {
    h2t ha, hb; __builtin_memcpy(&ha, &a, 4); __builtin_memcpy(&hb, &b, 4);
    return __builtin_amdgcn_fdot2(ha, hb, c, false);
}
// lane^1 (quad_perm [1,0,3,2] = 0xB1)
__device__ __forceinline__ float dpp_x1(float v) {
    int i; __builtin_memcpy(&i, &v, 4);
    int r = __builtin_amdgcn_update_dpp(0, i, 0xB1, 0xF, 0xF, true);
    float f; __builtin_memcpy(&f, &r, 4); return f;
}

template<int DIR>
__device__ __forceinline__ void run_dir(const float* __restrict__ x,
                                        const float* __restrict__ h0,
                                        const float* __restrict__ c0,
                                        const float* __restrict__ w_ih,
                                        const float* __restrict__ w_hh,
                                        const float* __restrict__ bi,
                                        const float* __restrict__ bh,
                                        float* __restrict__ out,
                                        float* __restrict__ h_n,
                                        float* __restrict__ c_n,
                                        int b2, int lane,
                                        int* xlds, int* hl)
{
    // lane = 20c + u : chain c (0/1), unit u. Lanes 40..63 idle (mirror chain 1).
    const int  c    = lane / 20;            // 0,1,2,3
    const int  u    = lane % 20;
    const int  cc   = (c < 2) ? c : 1;      // clamped chain for reads
    const bool act  = (c < 2);              // lanes that own a (chain, unit) output
    const int  bgl  = 2 * b2 + cc;          // global batch index

    // h publish: even lanes (u even) hold pair (h_u, h_{u+1}) after dpp_x1.
    // ALL lanes store every step (dump slots otherwise) -> stops LLVM from
    // CSE-hoisting the hl loads across steps (R9/R10 lesson).
    const bool okp  = act && ((u & 1) == 0);
    const int  offH = okp ? (cc * 16 + (u >> 1)) : (32 + lane);  // real 0..9 / 16..25, dump 32..95

    // ---- per-lane weights: all 4 gates of unit u, fp16-packed, pre-scaled ----
    // gates g = q*H + u, q = 0(i),1(f),2(g~),3(o); g~ row scaled by K2, others by -L2E
    int wh[4][10], wi[4][5]; float bias[4];
    #pragma unroll
    for (int q = 0; q < 4; ++q) {
        const float sc = (q == 2) ? K2 : (-L2E);
        const int g = q * H + u;
        #pragma unroll
        for (int k = 0; k < 10; ++k)
            wh[q][k] = pk(w_hh[g * H + 2 * k] * sc, w_hh[g * H + 2 * k + 1] * sc);
        #pragma unroll
        for (int k = 0; k < 5; ++k)
            wi[q][k] = pk(w_ih[g * IN + 2 * k] * sc, w_ih[g * IN + 2 * k + 1] * sc);
        bias[q] = (bi[g] + bh[g]) * sc;
    }

    float cv = c0[(DIR * BATCH + bgl) * H + u] * K2;   // carried pre-scaled
    float hv = h0[(DIR * BATCH + bgl) * H + u];

    // ---- x chunk staging: 320 fp16-pairs/chunk (2 chains x 5 pairs x 32 steps) ----
    // pair e (0..319): ss=e/10, j=e%10 -> chain j/5, pair j%5; global col = 2j of row.
    constexpr ptrdiff_t XSTEP = DIR ? -(ptrdiff_t)(BATCH * IN) : (ptrdiff_t)(BATCH * IN);
    constexpr ptrdiff_t XOFF0 = DIR ? (ptrdiff_t)(SEQ - 1) * (BATCH * IN) : 0;
    const float* xbase = x + (2 * b2) * IN + XOFF0;

    float2 pend[5];
    auto issue_chunk = [&](int s0) {
        #pragma unroll
        for (int i = 0; i < 5; ++i) {
            const int e = lane + 64 * i;               // 0..319 exactly
            pend[i] = *(const float2*)(xbase + (ptrdiff_t)(s0 + e / 10) * XSTEP + 2 * (e % 10));
        }
    };
    auto write_chunk = [&](int buf) {
        #pragma unroll
        for (int i = 0; i < 5; ++i) {
            const int e = lane + 64 * i;
            const int j = e % 10;
            xlds[buf * (XS * XRW) + (e / 10) * XRW + j + (j >= 5 ? 3 : 0)] = pk(pend[i].x, pend[i].y);
        }
    };
    auto read_x = [&](int buf, int ss, int (&xq)[5]) {
        const int* xr = &xlds[buf * (XS * XRW) + ss * XRW + cc * 8];
        const int4 xa = *(const int4*)xr;
        xq[0] = xa.x; xq[1] = xa.y; xq[2] = xa.z; xq[3] = xa.w; xq[4] = xr[4];
    };
    auto read_h = [&](int (&hp)[10]) {
        const int* hr = &hl[cc * 16];
        const int4 hA = *(const int4*)hr;
        const int4 hB = *(const int4*)(hr + 4);
        const int2 hC = *(const int2*)(hr + 8);
        hp[0]=hA.x; hp[1]=hA.y; hp[2]=hA.z; hp[3]=hA.w;
        hp[4]=hB.x; hp[5]=hB.y; hp[6]=hB.z; hp[7]=hB.w;
        hp[8]=hC.x; hp[9]=hC.y;
    };

    issue_chunk(0);  write_chunk(0);
    issue_chunk(XS);                                   // next chunk pending in regs

    // initial publish (pk/dpp at full exec), then prime hp and xq
    hl[offH] = pk(hv, dpp_x1(hv));
    int hp[10], xq[5];
    read_h(hp);
    read_x(0, 0, xq);

    // ---- out addressing: uniform row offset (SALU) + constant lane offset ----
    constexpr ptrdiff_t OSTEP = DIR ? -(ptrdiff_t)(BATCH * 2 * H) : (ptrdiff_t)(BATCH * 2 * H);
    ptrdiff_t           orow  = DIR ? (ptrdiff_t)(SEQ - 1) * (BATCH * 2 * H) : 0;
    const int           ocst  = bgl * (2 * H) + DIR * H + u;

    for (int s0 = 0; s0 < SEQ; s0 += XS) {
        const int buf = (s0 >> 5) & 1;
        #pragma unroll 4
        for (int ss = 0; ss < XS; ++ss) {
            // ---- prefetch x for NEXT step (independent of this step's compute) ----
            int xqn[5];
            if (ss < XS - 1) read_x(buf, ss + 1, xqn);

            // ---- 4 gates: x-dots first (hp read last step still landing), then h-dots ----
            float a0 = bias[0], a1 = bias[1], a2 = bias[2], a3 = bias[3];
            #pragma unroll
            for (int k = 0; k < 5; ++k) {
                a0 = dot2(xq[k], wi[0][k], a0);
                a1 = dot2(xq[k], wi[1][k], a1);
                a2 = dot2(xq[k], wi[2][k], a2);
                a3 = dot2(xq[k], wi[3][k], a3);
            }
            #pragma unroll
            for (int k = 0; k < 10; ++k) {
                a0 = dot2(hp[k], wh[0][k], a0);
                a1 = dot2(hp[k], wh[1][k], a1);
                a2 = dot2(hp[k], wh[2][k], a2);
                a3 = dot2(hp[k], wh[3][k], a3);
            }

            // ---- nonlinearities (uniform constants; weights pre-scaled) ----
            const float si = sig2(a0);                         // sigmoid(i)
            const float sf = sig2(a1);                         // sigmoid(f)
            const float n2 = fmaf(2.0f * K2, sig2(a2), -K2);   // K2 * tanh(g~)
            const float so = sig2(a3);                         // sigmoid(o)
            cv = fmaf(sf, cv, si * n2);                        // c' = f*c' + K2*i*tanh(g~)
            const float th = fmaf(2.0f, sig2(cv), -1.0f);      // tanh(c)  (c' = K2*c)
            hv = so * th;

            // ---- publish h pair (full-exec pk/dpp), then read next hp (in-order DS) ----
            hl[offH] = pk(hv, dpp_x1(hv));
            read_h(hp);

            if (act) __builtin_nontemporal_store(hv, out + orow + ocst);
            orow += OSTEP;

            if (ss < XS - 1) {
                #pragma unroll
                for (int k = 0; k < 5; ++k) xq[k] = xqn[k];
            }
        }
        // ---- chunk boundary: publish pending chunk, prefetch next-next, prime row 0 ----
        if (s0 + XS < SEQ) {
            write_chunk(buf ^ 1);                      // counted-vmcnt wait on old loads only
            if (s0 + 2 * XS < SEQ) issue_chunk(s0 + 2 * XS);
            read_x(buf ^ 1, 0, xq);
        }
    }

    if (act) {
        h_n[(DIR * BATCH + bgl) * H + u] = hv;
        c_n[(DIR * BATCH + bgl) * H + u] = cv * (1.0f / K2);
    }
}

__launch_bounds__(64)
__global__ void lstm_bidir(const float* __restrict__ x,
                           const float* __restrict__ h0,
                           const float* __restrict__ c0,
                           const float* __restrict__ w_ih_f, const float* __restrict__ w_hh_f,
                           const float* __restrict__ b_ih_f, const float* __restrict__ b_hh_f,
                           const float* __restrict__ w_ih_b, const float* __restrict__ w_hh_b,
                           const float* __restrict__ b_ih_b, const float* __restrict__ b_hh_b,
                           float* __restrict__ out, float* __restrict__ h_n, float* __restrict__ c_n)
{
    __shared__ __align__(16) int xlds[2 * XS * XRW];   // x chunks, fp16-pair packed (4 KiB)
    __shared__ __align__(16) int hl[96];               // h pairs c0:[0..9] c1:[16..25] + dumps

    const int b2   = blockIdx.x;                       // pair of batch elements
    const int lane = threadIdx.x;

    if (blockIdx.y == 0)
        run_dir<0>(x, h0, c0, w_ih_f, w_hh_f, b_ih_f, b_hh_f, out, h_n, c_n, b2, lane, xlds, hl);
    else
        run_dir<1>(x, h0, c0, w_ih_b, w_hh_b, b_ih_b, b_hh_b, out, h_n, c_n, b2, lane, xlds, hl);
}

} // namespace

extern "C" void kernel_launch(void* const* d_in, const int* in_sizes, int n_in,
                              void* d_out, int out_size, void* d_ws, size_t ws_size,
                              hipStream_t stream)
{
    const float* x      = (const float*)d_in[0];
    const float* h0     = (const float*)d_in[1];
    const float* c0     = (const float*)d_in[2];
    const float* w_ih_f = (const float*)d_in[3];
    const float* w_hh_f = (const float*)d_in[4];
    const float* b_ih_f = (const float*)d_in[5];
    const float* b_hh_f = (const float*)d_in[6];
    const float* w_ih_b = (const float*)d_in[7];
    const float* w_hh_b = (const float*)d_in[8];
    const float* b_ih_b = (const float*)d_in[9];
    const float* b_hh_b = (const float*)d_in[10];

    float* out = (float*)d_out;
    float* h_n = out + (size_t)SEQ * BATCH * 2 * H;
    float* c_n = h_n + (size_t)2 * BATCH * H;

    dim3 grid(BATCH / 2, 2), block(64);
    hipLaunchKernelGGL(lstm_bidir, grid, block, 0, stream,
                       x, h0, c0, w_ih_f, w_hh_f, b_ih_f, b_hh_f,
                       w_ih_b, w_hh_b, b_ih_b, b_hh_b, out, h_n, c_n);
}